// Round 14
// baseline (1643.085 us; speedup 1.0000x reference)
//
#include <hip/hip_runtime.h>

typedef __attribute__((ext_vector_type(8))) short bf16x8;
typedef __attribute__((ext_vector_type(4))) float f32x4;
typedef __attribute__((ext_vector_type(4))) unsigned int u32x4;
typedef __attribute__((ext_vector_type(4))) int i32x4;

__device__ __forceinline__ short f2bf(float f) {
  unsigned u = __float_as_uint(f);
  u = (u + 0x7fffu + ((u >> 16) & 1u)) >> 16;
  return (short)u;
}
__device__ __forceinline__ float bf2f(unsigned short u) {
  return __uint_as_float(((unsigned)u) << 16);
}
__device__ __forceinline__ unsigned cvtpk(float lo, float hi) {
  unsigned r;
  asm("v_cvt_pk_bf16_f32 %0, %1, %2" : "=v"(r) : "v"(lo), "v"(hi));
  return r;
}
__device__ __forceinline__ bf16x8 u2b(u32x4 w) {
  union { u32x4 u; bf16x8 b; } x; x.u = w; return x.b;
}

#define FILLB 2048
#define PACKB 40

// ---------------- fused prep: {XCD-local fill || node-GEMM layer1 || edge-W pack} ----------------
// Fill role: TRUE XCD partitioning. Each wave reads its physical XCD id
// (s_getreg HW_REG_XCC_ID, measured method m09) and drains the work queue of
// ITS partition (dst range) -> cursor atomics + csr_pad writes stay in the
// LOCAL 4MB L2 (slice = 50KB cursor + 3.2MB csr; streams are non-temporal so
// they don't evict it). Afterwards waves STEAL from other queues, so coverage
// is guaranteed under ANY block->XCD mapping (bad XCC read => slow, not wrong).
__global__ __launch_bounds__(256) void prep_k(
    const float* __restrict__ x, const float* __restrict__ W1,
    const float* __restrict__ Wm1, const float* __restrict__ Wm2,
    const int* __restrict__ src, const int* __restrict__ dst,
    unsigned* cursor, unsigned* wq, int* __restrict__ csr_pad,
    short* __restrict__ We1p, short* __restrict__ We2p,
    unsigned short* __restrict__ lin, int e, int n, int nNodeB)
{
  __shared__ __align__(16) short Wl[8192];
  const int tid = threadIdx.x;

  if (blockIdx.x < FILLB) {
    // ---- role A: queue-driven XCD-local fill ----
    unsigned xcc;
    asm volatile("s_getreg_b32 %0, hwreg(HW_REG_XCC_ID)" : "=s"(xcc));
    const int myp = (int)(xcc & 7u);
    const int lane = tid & 63;
    const int e4 = e >> 2;
    const i32x4* dst4 = (const i32x4*)dst;
    const i32x4* src4 = (const i32x4*)src;
    for (int q = 0; q < 8; ++q) {
      const int p  = (myp + q) & 7;
      const int lo = (int)(((long)n * p) >> 3);
      const int hi = (int)(((long)n * (p + 1)) >> 3);
      while (true) {
        int c = 0;
        if (lane == 0) c = (int)atomicAdd(&wq[p], 64u);
        c = __shfl(c, 0, 64);
        if (c >= e4) break;
        const int i = c + lane;
        if (i < e4) {
          i32x4 d = __builtin_nontemporal_load(&dst4[i]);
          i32x4 s = __builtin_nontemporal_load(&src4[i]);
          if (d[0] >= lo && d[0] < hi) { int ps = (int)atomicAdd(&cursor[d[0]], 1u); if (ps < 64) csr_pad[((size_t)d[0] << 6) + ps] = s[0]; }
          if (d[1] >= lo && d[1] < hi) { int ps = (int)atomicAdd(&cursor[d[1]], 1u); if (ps < 64) csr_pad[((size_t)d[1] << 6) + ps] = s[1]; }
          if (d[2] >= lo && d[2] < hi) { int ps = (int)atomicAdd(&cursor[d[2]], 1u); if (ps < 64) csr_pad[((size_t)d[2] << 6) + ps] = s[2]; }
          if (d[3] >= lo && d[3] < hi) { int ps = (int)atomicAdd(&cursor[d[3]], 1u); if (ps < 64) csr_pad[((size_t)d[3] << 6) + ps] = s[3]; }
        }
      }
    }
    // tail edges (e not multiple of 4) via dedicated queue
    const int etail = e - (e4 << 2);
    while (etail > 0) {
      int c = 0;
      if (lane == 0) c = (int)atomicAdd(&wq[8], 1u);
      c = __shfl(c, 0, 64);
      if (c >= etail) break;
      if (lane == 0) {
        int i = (e4 << 2) + c;
        int d = dst[i];
        int ps = (int)atomicAdd(&cursor[d], 1u);
        if (ps < 64) csr_pad[((size_t)d << 6) + ps] = src[i];
      }
    }
  } else if (blockIdx.x < FILLB + nNodeB) {
    // ---- role B: layer-1 node GEMM lin = bf16(x @ W1), W1 packed inline ----
    const int nb = blockIdx.x - FILLB;
    for (int i = tid; i < 8192; i += 256) {
      int j = i & 7, l = (i >> 3) & 63, c = (i >> 9) & 3, kk = i >> 11;
      int row = kk * 32 + ((l >> 4) * 8) + j, col = c * 16 + (l & 15);
      Wl[i] = f2bf(W1[row * 64 + col]);
    }
    __syncthreads();
    const int lane = tid & 63;
    const int wid  = tid >> 6;
    const int g    = lane >> 4;
    const int r16  = lane & 15;
    const int base = nb * 64 + wid * 16;
    if (base < n) {
      int arow = base + r16;
      if (arow >= n) arow = n - 1;
      const bf16x8* wb = (const bf16x8*)Wl;
      f32x4 acc[4];
      #pragma unroll
      for (int c = 0; c < 4; ++c) acc[c] = (f32x4){0.f, 0.f, 0.f, 0.f};
      #pragma unroll
      for (int kk = 0; kk < 4; ++kk) {
        const float4* af = (const float4*)(x + (size_t)arow * 128 + kk * 32 + 8 * g);
        float4 u = af[0], v = af[1];
        u32x4 w;
        w[0] = cvtpk(u.x, u.y); w[1] = cvtpk(u.z, u.w);
        w[2] = cvtpk(v.x, v.y); w[3] = cvtpk(v.z, v.w);
        bf16x8 a = u2b(w);
        #pragma unroll
        for (int c = 0; c < 4; ++c)
          acc[c] = __builtin_amdgcn_mfma_f32_16x16x32_bf16(a, wb[(kk * 4 + c) * 64 + lane], acc[c], 0, 0, 0);
      }
      #pragma unroll
      for (int rr = 0; rr < 4; ++rr) {
        int orow = base + g * 4 + rr;
        if (orow < n) {
          unsigned short* cp = lin + (size_t)orow * 64 + r16;
          cp[0]  = (unsigned short)f2bf(acc[0][rr]);
          cp[16] = (unsigned short)f2bf(acc[1][rr]);
          cp[32] = (unsigned short)f2bf(acc[2][rr]);
          cp[48] = (unsigned short)f2bf(acc[3][rr]);
        }
      }
    }
  } else {
    // ---- role C: pack edge-MLP weights (permuted A-pack, proven) ----
    const int t = (blockIdx.x - FILLB - nNodeB) * 256 + tid;
    const int stride = PACKB * 256;
    for (int i = t; i < 10240; i += stride) {
      int j = i & 7, l = (i >> 3) & 63, c = (i >> 9) & 3, kk = i >> 11;
      int row = kk * 32 + ((l >> 4) * 8) + j;
      int r_ = l & 15;
      int col = 32 * (c >> 1) + 8 * (r_ >> 2) + 4 * (c & 1) + (r_ & 3);
      We1p[i] = f2bf(row < 144 ? Wm1[row * 64 + col] : 0.f);
    }
    for (int i = t; i < 2048; i += stride) {
      int j = i & 7, l = (i >> 3) & 63, c = (i >> 9) & 1, kk = (i >> 10) & 1;
      int row = kk * 32 + ((l >> 4) * 8) + j, col = c * 16 + (l & 15);
      We2p[i] = f2bf(Wm2[row * 32 + col]);
    }
  }
}

// ---------------- layer-1 aggregation: h1' = relu(A_hat lin + b) * dinv (scaled out) ----------------
__global__ __launch_bounds__(256) void agg_csr_k(
    const unsigned short* __restrict__ lin, const unsigned* __restrict__ deg,
    const int* __restrict__ csr_pad, const float* __restrict__ bias,
    unsigned short* __restrict__ out, int n)
{
  const int node = blockIdx.x * 4 + (threadIdx.x >> 6);
  if (node >= n) return;
  const int lane = threadIdx.x & 63;
  const int es = lane >> 4;
  const int fq = lane & 15;
  const float dn = rsqrtf((float)(deg[node] + 1u));
  const int cnt = (int)deg[node];
  const int* sp = csr_pad + ((size_t)node << 6);
  float ax = 0.f, ay = 0.f, az = 0.f, aw = 0.f;
  if (es == 0) {
    ushort4 v = *(const ushort4*)(lin + (size_t)node * 64 + fq * 4);
    float w = dn * dn;
    ax = w * bf2f(v.x); ay = w * bf2f(v.y); az = w * bf2f(v.z); aw = w * bf2f(v.w);
  }
  #pragma unroll 4
  for (int j = es; j < cnt; j += 4) {
    int s = sp[j];
    float w = rsqrtf((float)(deg[s] + 1u)) * dn;
    ushort4 v = *(const ushort4*)(lin + (size_t)s * 64 + fq * 4);
    ax += w * bf2f(v.x); ay += w * bf2f(v.y);
    az += w * bf2f(v.z); aw += w * bf2f(v.w);
  }
  ax += __shfl_xor(ax, 16, 64); ax += __shfl_xor(ax, 32, 64);
  ay += __shfl_xor(ay, 16, 64); ay += __shfl_xor(ay, 32, 64);
  az += __shfl_xor(az, 16, 64); az += __shfl_xor(az, 32, 64);
  aw += __shfl_xor(aw, 16, 64); aw += __shfl_xor(aw, 32, 64);
  if (es == 0) {
    float4 b = *(const float4*)(bias + fq * 4);
    ushort4 o;   // store PRE-SCALED h' = relu(.)*dinv  (folding: A_hat h == dn*sum h'[s])
    o.x = (unsigned short)f2bf(fmaxf(ax + b.x, 0.f) * dn);
    o.y = (unsigned short)f2bf(fmaxf(ay + b.y, 0.f) * dn);
    o.z = (unsigned short)f2bf(fmaxf(az + b.z, 0.f) * dn);
    o.w = (unsigned short)f2bf(fmaxf(aw + b.w, 0.f) * dn);
    *(ushort4*)(out + (size_t)node * 64 + fq * 4) = o;
  }
}

// ---------------- fused agg+GEMM layers 2/3 (input h is PRE-SCALED) ----------------
// inner loop = pure adds (dinv[s] already folded into h'); one *dn at the end.
template<int SCALE_OUT>
__global__ __launch_bounds__(256) void agg_gemm_k(
    const unsigned short* __restrict__ h_in, const unsigned* __restrict__ deg,
    const int* __restrict__ csr_pad, const float* __restrict__ W,
    const float* __restrict__ bias, unsigned short* __restrict__ h_out, int n)
{
  __shared__ __align__(16) short Wl[4096];
  __shared__ __align__(16) short X[4][16][72];
  const int tid = threadIdx.x;
  for (int i = tid; i < 4096; i += 256) {
    int j = i & 7, l = (i >> 3) & 63, c = (i >> 9) & 3, kk = i >> 11;
    int row = kk * 32 + ((l >> 4) * 8) + j, col = c * 16 + (l & 15);
    Wl[i] = f2bf(W[row * 64 + col]);
  }
  const int lane = tid & 63;
  const int wid  = tid >> 6;
  const int es   = lane >> 4;
  const int fq   = lane & 15;
  const int base = blockIdx.x * 64 + wid * 16;

  // ---- phase A: aggregate 16 nodes into X[wid]; X = dn * (self' + sum h'[s]) ----
  for (int nd = 0; nd < 16; ++nd) {
    int node = base + nd;
    if (node >= n) node = n - 1;
    const float dn = rsqrtf((float)(deg[node] + 1u));
    const int cnt = (int)deg[node];
    const int* sp = csr_pad + ((size_t)node << 6);
    float ax = 0.f, ay = 0.f, az = 0.f, aw = 0.f;
    if (es == 0) {
      ushort4 v = *(const ushort4*)(h_in + (size_t)node * 64 + fq * 4);
      ax = bf2f(v.x); ay = bf2f(v.y); az = bf2f(v.z); aw = bf2f(v.w);
    }
    #pragma unroll 4
    for (int j = es; j < cnt; j += 4) {
      int s = sp[j];
      ushort4 v = *(const ushort4*)(h_in + (size_t)s * 64 + fq * 4);
      ax += bf2f(v.x); ay += bf2f(v.y);
      az += bf2f(v.z); aw += bf2f(v.w);
    }
    ax += __shfl_xor(ax, 16, 64); ax += __shfl_xor(ax, 32, 64);
    ay += __shfl_xor(ay, 16, 64); ay += __shfl_xor(ay, 32, 64);
    az += __shfl_xor(az, 16, 64); az += __shfl_xor(az, 32, 64);
    aw += __shfl_xor(aw, 16, 64); aw += __shfl_xor(aw, 32, 64);
    if (es == 0) {
      ushort4 o;
      o.x = (unsigned short)f2bf(ax * dn); o.y = (unsigned short)f2bf(ay * dn);
      o.z = (unsigned short)f2bf(az * dn); o.w = (unsigned short)f2bf(aw * dn);
      *(ushort4*)&X[wid][nd][fq * 4] = o;
    }
  }
  __syncthreads();

  // ---- phase B: [16 nodes] @ W via 8 MFMAs; epilogue optionally pre-scales for next layer ----
  const int g = es, r16 = fq;
  float bcol[4];
  #pragma unroll
  for (int c = 0; c < 4; ++c) bcol[c] = bias[c * 16 + r16];
  const bf16x8* wb = (const bf16x8*)Wl;
  f32x4 acc[4];
  #pragma unroll
  for (int c = 0; c < 4; ++c) acc[c] = (f32x4){bcol[c], bcol[c], bcol[c], bcol[c]};
  #pragma unroll
  for (int kk = 0; kk < 2; ++kk) {
    bf16x8 a = *(const bf16x8*)&X[wid][r16][kk * 32 + 8 * g];
    #pragma unroll
    for (int c = 0; c < 4; ++c)
      acc[c] = __builtin_amdgcn_mfma_f32_16x16x32_bf16(a, wb[(kk * 4 + c) * 64 + lane], acc[c], 0, 0, 0);
  }
  #pragma unroll
  for (int rr = 0; rr < 4; ++rr) {
    int orow = base + g * 4 + rr;
    if (orow < n) {
      float so = SCALE_OUT ? rsqrtf((float)(deg[orow] + 1u)) : 1.f;
      unsigned short* cp = h_out + (size_t)orow * 64 + r16;
      cp[0]  = (unsigned short)f2bf(fmaxf(acc[0][rr], 0.f) * so);
      cp[16] = (unsigned short)f2bf(fmaxf(acc[1][rr], 0.f) * so);
      cp[32] = (unsigned short)f2bf(fmaxf(acc[2][rr], 0.f) * so);
      cp[48] = (unsigned short)f2bf(fmaxf(acc[3][rr], 0.f) * so);
    }
  }
}

// ---------------- edge MLP: swapped-operand MFMA, zero LDS, weights in registers ----------------
// NOTE: __launch_bounds__(256) only — R10: a min-waves arg crushes VGPR and
// evicts the 24 register-resident weight frags (FETCH 208MB->1.25GB, 4x slower).
__global__ __launch_bounds__(256) void edge_mlp_mfma_k(
    const unsigned short* __restrict__ hb, const float* __restrict__ ea,
    const int* __restrict__ src, const int* __restrict__ dst,
    const short* __restrict__ W1p, const short* __restrict__ W2p,
    const float* __restrict__ bm1, const float* __restrict__ bm2,
    const float* __restrict__ Wm3, const float* __restrict__ bm3,
    float* __restrict__ out, int E, int ntiles)
{
  const int tid  = threadIdx.x;
  const int lane = tid & 63;
  const int wid  = tid >> 6;
  const int g    = lane >> 4;
  const int r16  = lane & 15;

  bf16x8 w1f[20];
  #pragma unroll
  for (int t = 0; t < 20; ++t) w1f[t] = ((const bf16x8*)W1p)[t * 64 + lane];
  bf16x8 w2f[4];
  #pragma unroll
  for (int t = 0; t < 4; ++t) w2f[t] = ((const bf16x8*)W2p)[t * 64 + lane];

  f32x4 b1v[4];
  #pragma unroll
  for (int c = 0; c < 4; ++c) {
    float4 v = *(const float4*)(bm1 + 32 * (c >> 1) + 8 * g + 4 * (c & 1));
    b1v[c] = (f32x4){v.x, v.y, v.z, v.w};
  }
  f32x4 b2v[2];
  #pragma unroll
  for (int c = 0; c < 2; ++c) {
    float4 v = *(const float4*)(bm2 + c * 16 + 4 * g);
    b2v[c] = (f32x4){v.x, v.y, v.z, v.w};
  }
  float4 w3a[2], w3b[2];
  #pragma unroll
  for (int c = 0; c < 2; ++c) {
    w3a[c] = *(const float4*)(Wm3 + (c * 16 + 4 * g) * 2);
    w3b[c] = *(const float4*)(Wm3 + (c * 16 + 4 * g) * 2 + 4);
  }
  const float b30 = bm3[0], b31 = bm3[1];

  const int ngroups = (ntiles + 3) >> 2;
  if (blockIdx.x >= ngroups) return;

  int mye1, sl1, dl1;
  bf16x8 c_a0, c_a1, c_a2, c_a3;
  float4 c_e0, c_e1;
  {
    int e = (blockIdx.x * 4 + wid) * 16 + r16;
    int mye = (e < E) ? e : (E - 1);
    int sl = src[mye], dl = dst[mye];
    const bf16x8* hs = (const bf16x8*)(hb + (size_t)sl * 64);
    c_a0 = hs[g]; c_a1 = hs[4 + g];
    const bf16x8* hd = (const bf16x8*)(hb + (size_t)dl * 64);
    c_a2 = hd[g]; c_a3 = hd[4 + g];
    if (g < 2) {
      const float4* ep = (const float4*)(ea + (size_t)mye * 16 + 8 * g);
      c_e0 = ep[0]; c_e1 = ep[1];
    }
    int grp1 = blockIdx.x + gridDim.x;
    if (grp1 > ngroups - 1) grp1 = ngroups - 1;
    int e1 = (grp1 * 4 + wid) * 16 + r16;
    mye1 = (e1 < E) ? e1 : (E - 1);
    sl1 = src[mye1]; dl1 = dst[mye1];
  }

  for (int grp = blockIdx.x; grp < ngroups; grp += gridDim.x) {
    const int e0 = (grp * 4 + wid) * 16;

    bf16x8 n_a0, n_a1, n_a2, n_a3;
    float4 n_e0, n_e1;
    {
      const bf16x8* hs = (const bf16x8*)(hb + (size_t)sl1 * 64);
      n_a0 = hs[g]; n_a1 = hs[4 + g];
      const bf16x8* hd = (const bf16x8*)(hb + (size_t)dl1 * 64);
      n_a2 = hd[g]; n_a3 = hd[4 + g];
      if (g < 2) {
        const float4* ep = (const float4*)(ea + (size_t)mye1 * 16 + 8 * g);
        n_e0 = ep[0]; n_e1 = ep[1];
      }
    }
    int mye2, sl2, dl2;
    {
      int grp2 = grp + 2 * gridDim.x;
      if (grp2 > ngroups - 1) grp2 = ngroups - 1;
      int e2 = (grp2 * 4 + wid) * 16 + r16;
      mye2 = (e2 < E) ? e2 : (E - 1);
      sl2 = src[mye2]; dl2 = dst[mye2];
    }

    bf16x8 a4;
    if (g < 2) {
      u32x4 w;
      w[0] = cvtpk(c_e0.x, c_e0.y); w[1] = cvtpk(c_e0.z, c_e0.w);
      w[2] = cvtpk(c_e1.x, c_e1.y); w[3] = cvtpk(c_e1.z, c_e1.w);
      a4 = u2b(w);
    } else {
      a4 = (bf16x8){0, 0, 0, 0, 0, 0, 0, 0};
    }

    f32x4 acc[4];
    #pragma unroll
    for (int c = 0; c < 4; ++c) acc[c] = b1v[c];
    #pragma unroll
    for (int c = 0; c < 4; ++c) {
      acc[c] = __builtin_amdgcn_mfma_f32_16x16x32_bf16(w1f[0 * 4 + c], c_a0, acc[c], 0, 0, 0);
      acc[c] = __builtin_amdgcn_mfma_f32_16x16x32_bf16(w1f[1 * 4 + c], c_a1, acc[c], 0, 0, 0);
      acc[c] = __builtin_amdgcn_mfma_f32_16x16x32_bf16(w1f[2 * 4 + c], c_a2, acc[c], 0, 0, 0);
      acc[c] = __builtin_amdgcn_mfma_f32_16x16x32_bf16(w1f[3 * 4 + c], c_a3, acc[c], 0, 0, 0);
      acc[c] = __builtin_amdgcn_mfma_f32_16x16x32_bf16(w1f[4 * 4 + c], a4,   acc[c], 0, 0, 0);
    }

    u32x4 x0w, x1w;
    x0w[0] = cvtpk(fmaxf(acc[0][0], 0.f), fmaxf(acc[0][1], 0.f));
    x0w[1] = cvtpk(fmaxf(acc[0][2], 0.f), fmaxf(acc[0][3], 0.f));
    x0w[2] = cvtpk(fmaxf(acc[1][0], 0.f), fmaxf(acc[1][1], 0.f));
    x0w[3] = cvtpk(fmaxf(acc[1][2], 0.f), fmaxf(acc[1][3], 0.f));
    x1w[0] = cvtpk(fmaxf(acc[2][0], 0.f), fmaxf(acc[2][1], 0.f));
    x1w[1] = cvtpk(fmaxf(acc[2][2], 0.f), fmaxf(acc[2][3], 0.f));
    x1w[2] = cvtpk(fmaxf(acc[3][0], 0.f), fmaxf(acc[3][1], 0.f));
    x1w[3] = cvtpk(fmaxf(acc[3][2], 0.f), fmaxf(acc[3][3], 0.f));
    bf16x8 xa0 = u2b(x0w), xa1 = u2b(x1w);

    f32x4 acc2[2];
    #pragma unroll
    for (int c = 0; c < 2; ++c) acc2[c] = b2v[c];
    #pragma unroll
    for (int c = 0; c < 2; ++c) {
      acc2[c] = __builtin_amdgcn_mfma_f32_16x16x32_bf16(w2f[0 * 2 + c], xa0, acc2[c], 0, 0, 0);
      acc2[c] = __builtin_amdgcn_mfma_f32_16x16x32_bf16(w2f[1 * 2 + c], xa1, acc2[c], 0, 0, 0);
    }

    float p0 = 0.f, p1 = 0.f;
    #pragma unroll
    for (int c = 0; c < 2; ++c) {
      float v0 = fmaxf(acc2[c][0], 0.f);
      float v1 = fmaxf(acc2[c][1], 0.f);
      float v2 = fmaxf(acc2[c][2], 0.f);
      float v3 = fmaxf(acc2[c][3], 0.f);
      p0 = fmaf(v0, w3a[c].x, p0); p1 = fmaf(v0, w3a[c].y, p1);
      p0 = fmaf(v1, w3a[c].z, p0); p1 = fmaf(v1, w3a[c].w, p1);
      p0 = fmaf(v2, w3b[c].x, p0); p1 = fmaf(v2, w3b[c].y, p1);
      p0 = fmaf(v3, w3b[c].z, p0); p1 = fmaf(v3, w3b[c].w, p1);
    }
    p0 += __shfl_xor(p0, 16, 64); p0 += __shfl_xor(p0, 32, 64);
    p1 += __shfl_xor(p1, 16, 64); p1 += __shfl_xor(p1, 32, 64);
    if (g == 0) {
      int e = e0 + r16;
      if (e < E) {
        float2 o; o.x = p0 + b30; o.y = p1 + b31;
        *(float2*)(out + (size_t)e * 2) = o;
      }
    }

    c_a0 = n_a0; c_a1 = n_a1; c_a2 = n_a2; c_a3 = n_a3;
    c_e0 = n_e0; c_e1 = n_e1;
    mye1 = mye2; sl1 = sl2; dl1 = dl2;
  }
}

// ---------------- launch ----------------
extern "C" void kernel_launch(void* const* d_in, const int* in_sizes, int n_in,
                              void* d_out, int out_size, void* d_ws, size_t ws_size,
                              hipStream_t stream) {
  const float* x   = (const float*)d_in[0];
  const int*   ei  = (const int*)d_in[1];
  const float* ea  = (const float*)d_in[2];
  const float* W1  = (const float*)d_in[3];
  const float* b1  = (const float*)d_in[4];
  const float* W2  = (const float*)d_in[5];
  const float* b2  = (const float*)d_in[6];
  const float* W3  = (const float*)d_in[7];
  const float* b3  = (const float*)d_in[8];
  const float* Wm1 = (const float*)d_in[9];
  const float* bm1 = (const float*)d_in[10];
  const float* Wm2 = (const float*)d_in[11];
  const float* bm2 = (const float*)d_in[12];
  const float* Wm3 = (const float*)d_in[13];
  const float* bm3 = (const float*)d_in[14];

  const int N  = in_sizes[0] / 128;
  const int E  = in_sizes[1] / 2;
  const int* srcp = ei;
  const int* dstp = ei + E;

  float* ws = (float*)d_ws;
  size_t off = 0;
  unsigned* cursor  = (unsigned*)(ws + off);  off += (size_t)N;
  unsigned* wq      = (unsigned*)(ws + off);  off += 16;
  int*      csr_pad = (int*)(ws + off);       off += (size_t)N * 64;
  unsigned short* lin = (unsigned short*)(ws + off); off += (size_t)N * 32;
  unsigned short* hA  = (unsigned short*)(ws + off); off += (size_t)N * 32;
  unsigned short* hB  = (unsigned short*)(ws + off); off += (size_t)N * 32;
  short* We1p = (short*)(ws + off); off += 5120;
  short* We2p = (short*)(ws + off); off += 1024;

  const int gNode = (N + 63) / 64;
  const int gAgg  = (N + 3) / 4;
  const int ntiles = (E + 15) / 16;

  (void)hipMemsetAsync(cursor, 0, ((size_t)N + 16) * 4, stream);

  // fused prep: XCD-local queue fill || layer-1 GEMM || edge-weight pack
  prep_k<<<FILLB + gNode + PACKB, 256, 0, stream>>>(
      x, W1, Wm1, Wm2, srcp, dstp, cursor, wq, csr_pad, We1p, We2p, lin, E, N, gNode);

  // layer 1 aggregate (outputs pre-scaled h1' = relu(.)*dinv)
  agg_csr_k<<<gAgg, 256, 0, stream>>>(lin, cursor, csr_pad, b1, hA, N);
  // layers 2,3: fused agg+GEMM; inner loop pure adds (dinv folded)
  agg_gemm_k<1><<<gNode, 256, 0, stream>>>(hA, cursor, csr_pad, W2, b2, hB, N);
  agg_gemm_k<0><<<gNode, 256, 0, stream>>>(hB, cursor, csr_pad, W3, b3, hA, N);

  // edge classifier
  edge_mlp_mfma_k<<<2048, 256, 0, stream>>>(hA, ea, srcp, dstp, We1p, We2p,
      bm1, bm2, Wm3, bm3, (float*)d_out, E, ntiles);
}

// Round 15
// 357.497 us; speedup vs baseline: 4.5961x; 4.5961x over previous
//
#include <hip/hip_runtime.h>

typedef __attribute__((ext_vector_type(8))) short bf16x8;
typedef __attribute__((ext_vector_type(4))) float f32x4;
typedef __attribute__((ext_vector_type(4))) unsigned int u32x4;

__device__ __forceinline__ short f2bf(float f) {
  unsigned u = __float_as_uint(f);
  u = (u + 0x7fffu + ((u >> 16) & 1u)) >> 16;
  return (short)u;
}
__device__ __forceinline__ float bf2f(unsigned short u) {
  return __uint_as_float(((unsigned)u) << 16);
}
__device__ __forceinline__ unsigned cvtpk(float lo, float hi) {
  unsigned r;
  asm("v_cvt_pk_bf16_f32 %0, %1, %2" : "=v"(r) : "v"(lo), "v"(hi));
  return r;
}
__device__ __forceinline__ bf16x8 u2b(u32x4 w) {
  union { u32x4 u; bf16x8 b; } x; x.u = w; return x.b;
}

// ---------------- padded-CSR fill (blockIdx&7 heuristic partition — R11 proven) ----------------
// R13/R14 post-mortem: TRUE XCD-local fill via XCC_ID + work queues serialized on
// a single cache line of queue counters (1350us). The simple blockIdx&7 range
// filter (correctness-independent heuristic) remains the best measured (~35-40us).
__global__ __launch_bounds__(256) void fill_pad_k(const int* __restrict__ src,
                                                  const int* __restrict__ dst,
                                                  unsigned* cursor,
                                                  int* __restrict__ csr_pad, int e, int n) {
  const int part  = blockIdx.x & 7;
  const int lo    = (int)(((long)n * part) >> 3);
  const int hi    = (int)(((long)n * (part + 1)) >> 3);
  const int nb    = gridDim.x >> 3;
  const int brank = blockIdx.x >> 3;
  const long stride = (long)nb * 256;
  const int e4 = e >> 2;
  const int4* dst4 = (const int4*)dst;
  for (long i = (long)brank * 256 + threadIdx.x; i < e4; i += stride) {
    int4 d = dst4[i];
    long eb = i * 4;
    if (d.x >= lo && d.x < hi) { int p = (int)atomicAdd(&cursor[d.x], 1u); if (p < 64) csr_pad[((size_t)d.x << 6) + p] = src[eb]; }
    if (d.y >= lo && d.y < hi) { int p = (int)atomicAdd(&cursor[d.y], 1u); if (p < 64) csr_pad[((size_t)d.y << 6) + p] = src[eb + 1]; }
    if (d.z >= lo && d.z < hi) { int p = (int)atomicAdd(&cursor[d.z], 1u); if (p < 64) csr_pad[((size_t)d.z << 6) + p] = src[eb + 2]; }
    if (d.w >= lo && d.w < hi) { int p = (int)atomicAdd(&cursor[d.w], 1u); if (p < 64) csr_pad[((size_t)d.w << 6) + p] = src[eb + 3]; }
  }
  for (long i = (long)e4 * 4 + (long)brank * 256 + threadIdx.x; i < e; i += stride) {
    int d = dst[i];
    if (d >= lo && d < hi) { int p = (int)atomicAdd(&cursor[d], 1u); if (p < 64) csr_pad[((size_t)d << 6) + p] = src[i]; }
  }
}

// ---------------- pack edge-MLP weights only (node W packed inline elsewhere) ----------------
__global__ void pack_edge_k(const float* __restrict__ Wm1, const float* __restrict__ Wm2,
                            short* __restrict__ We1p, short* __restrict__ We2p) {
  const int t = blockIdx.x * 256 + threadIdx.x;
  const int stride = gridDim.x * 256;
  for (int i = t; i < 10240; i += stride) {
    int j = i & 7, l = (i >> 3) & 63, c = (i >> 9) & 3, kk = i >> 11;
    int row = kk * 32 + ((l >> 4) * 8) + j;
    int r_ = l & 15;
    int col = 32 * (c >> 1) + 8 * (r_ >> 2) + 4 * (c & 1) + (r_ & 3);
    We1p[i] = f2bf(row < 144 ? Wm1[row * 64 + col] : 0.f);
  }
  for (int i = t; i < 2048; i += stride) {
    int j = i & 7, l = (i >> 3) & 63, c = (i >> 9) & 1, kk = (i >> 10) & 1;
    int row = kk * 32 + ((l >> 4) * 8) + j, col = c * 16 + (l & 15);
    We2p[i] = f2bf(Wm2[row * 32 + col]);
  }
}

// ---------------- layer-1 node GEMM: lin = bf16(x @ W1), W1 packed inline (R12-proven) ----------------
__global__ __launch_bounds__(256) void node_mfma_k(
    const float* __restrict__ x, const float* __restrict__ W1,
    unsigned short* __restrict__ lin, int n)
{
  __shared__ __align__(16) short Wl[8192];
  const int tid = threadIdx.x;
  for (int i = tid; i < 8192; i += 256) {
    int j = i & 7, l = (i >> 3) & 63, c = (i >> 9) & 3, kk = i >> 11;
    int row = kk * 32 + ((l >> 4) * 8) + j, col = c * 16 + (l & 15);
    Wl[i] = f2bf(W1[row * 64 + col]);
  }
  __syncthreads();
  const int lane = tid & 63;
  const int wid  = tid >> 6;
  const int g    = lane >> 4;
  const int r16  = lane & 15;
  const int base = blockIdx.x * 64 + wid * 16;
  if (base >= n) return;
  int arow = base + r16;
  if (arow >= n) arow = n - 1;
  const bf16x8* wb = (const bf16x8*)Wl;
  f32x4 acc[4];
  #pragma unroll
  for (int c = 0; c < 4; ++c) acc[c] = (f32x4){0.f, 0.f, 0.f, 0.f};
  #pragma unroll
  for (int kk = 0; kk < 4; ++kk) {
    const float4* af = (const float4*)(x + (size_t)arow * 128 + kk * 32 + 8 * g);
    float4 u = af[0], v = af[1];
    u32x4 w;
    w[0] = cvtpk(u.x, u.y); w[1] = cvtpk(u.z, u.w);
    w[2] = cvtpk(v.x, v.y); w[3] = cvtpk(v.z, v.w);
    bf16x8 a = u2b(w);
    #pragma unroll
    for (int c = 0; c < 4; ++c)
      acc[c] = __builtin_amdgcn_mfma_f32_16x16x32_bf16(a, wb[(kk * 4 + c) * 64 + lane], acc[c], 0, 0, 0);
  }
  #pragma unroll
  for (int rr = 0; rr < 4; ++rr) {
    int orow = base + g * 4 + rr;
    if (orow < n) {
      unsigned short* cp = lin + (size_t)orow * 64 + r16;
      cp[0]  = (unsigned short)f2bf(acc[0][rr]);
      cp[16] = (unsigned short)f2bf(acc[1][rr]);
      cp[32] = (unsigned short)f2bf(acc[2][rr]);
      cp[48] = (unsigned short)f2bf(acc[3][rr]);
    }
  }
}

// ---------------- layer-1 aggregation: h1' = relu(A_hat lin + b) * dinv (pre-scaled out) ----------------
__global__ __launch_bounds__(256) void agg_csr_k(
    const unsigned short* __restrict__ lin, const unsigned* __restrict__ deg,
    const int* __restrict__ csr_pad, const float* __restrict__ bias,
    unsigned short* __restrict__ out, int n)
{
  const int node = blockIdx.x * 4 + (threadIdx.x >> 6);
  if (node >= n) return;
  const int lane = threadIdx.x & 63;
  const int es = lane >> 4;
  const int fq = lane & 15;
  const float dn = rsqrtf((float)(deg[node] + 1u));
  const int cnt = (int)deg[node];
  const int* sp = csr_pad + ((size_t)node << 6);
  float ax = 0.f, ay = 0.f, az = 0.f, aw = 0.f;
  if (es == 0) {
    ushort4 v = *(const ushort4*)(lin + (size_t)node * 64 + fq * 4);
    float w = dn * dn;
    ax = w * bf2f(v.x); ay = w * bf2f(v.y); az = w * bf2f(v.z); aw = w * bf2f(v.w);
  }
  #pragma unroll 4
  for (int j = es; j < cnt; j += 4) {
    int s = sp[j];
    float w = rsqrtf((float)(deg[s] + 1u)) * dn;
    ushort4 v = *(const ushort4*)(lin + (size_t)s * 64 + fq * 4);
    ax += w * bf2f(v.x); ay += w * bf2f(v.y);
    az += w * bf2f(v.z); aw += w * bf2f(v.w);
  }
  ax += __shfl_xor(ax, 16, 64); ax += __shfl_xor(ax, 32, 64);
  ay += __shfl_xor(ay, 16, 64); ay += __shfl_xor(ay, 32, 64);
  az += __shfl_xor(az, 16, 64); az += __shfl_xor(az, 32, 64);
  aw += __shfl_xor(aw, 16, 64); aw += __shfl_xor(aw, 32, 64);
  if (es == 0) {
    float4 b = *(const float4*)(bias + fq * 4);
    ushort4 o;   // store PRE-SCALED h' = relu(.)*dinv  (A_hat h == dn*(h'_self + sum h'[s]))
    o.x = (unsigned short)f2bf(fmaxf(ax + b.x, 0.f) * dn);
    o.y = (unsigned short)f2bf(fmaxf(ay + b.y, 0.f) * dn);
    o.z = (unsigned short)f2bf(fmaxf(az + b.z, 0.f) * dn);
    o.w = (unsigned short)f2bf(fmaxf(aw + b.w, 0.f) * dn);
    *(ushort4*)(out + (size_t)node * 64 + fq * 4) = o;
  }
}

// ---------------- fused agg+GEMM layers 2/3 (input PRE-SCALED -> pure-add inner loop) ----------------
template<int SCALE_OUT>
__global__ __launch_bounds__(256) void agg_gemm_k(
    const unsigned short* __restrict__ h_in, const unsigned* __restrict__ deg,
    const int* __restrict__ csr_pad, const float* __restrict__ W,
    const float* __restrict__ bias, unsigned short* __restrict__ h_out, int n)
{
  __shared__ __align__(16) short Wl[4096];
  __shared__ __align__(16) short X[4][16][72];
  const int tid = threadIdx.x;
  for (int i = tid; i < 4096; i += 256) {
    int j = i & 7, l = (i >> 3) & 63, c = (i >> 9) & 3, kk = i >> 11;
    int row = kk * 32 + ((l >> 4) * 8) + j, col = c * 16 + (l & 15);
    Wl[i] = f2bf(W[row * 64 + col]);
  }
  const int lane = tid & 63;
  const int wid  = tid >> 6;
  const int es   = lane >> 4;
  const int fq   = lane & 15;
  const int base = blockIdx.x * 64 + wid * 16;

  // ---- phase A: aggregate 16 nodes into X[wid]; X = dn * (self' + sum h'[s]) ----
  for (int nd = 0; nd < 16; ++nd) {
    int node = base + nd;
    if (node >= n) node = n - 1;
    const float dn = rsqrtf((float)(deg[node] + 1u));
    const int cnt = (int)deg[node];
    const int* sp = csr_pad + ((size_t)node << 6);
    float ax = 0.f, ay = 0.f, az = 0.f, aw = 0.f;
    if (es == 0) {
      ushort4 v = *(const ushort4*)(h_in + (size_t)node * 64 + fq * 4);
      ax = bf2f(v.x); ay = bf2f(v.y); az = bf2f(v.z); aw = bf2f(v.w);
    }
    #pragma unroll 4
    for (int j = es; j < cnt; j += 4) {
      int s = sp[j];
      ushort4 v = *(const ushort4*)(h_in + (size_t)s * 64 + fq * 4);
      ax += bf2f(v.x); ay += bf2f(v.y);
      az += bf2f(v.z); aw += bf2f(v.w);
    }
    ax += __shfl_xor(ax, 16, 64); ax += __shfl_xor(ax, 32, 64);
    ay += __shfl_xor(ay, 16, 64); ay += __shfl_xor(ay, 32, 64);
    az += __shfl_xor(az, 16, 64); az += __shfl_xor(az, 32, 64);
    aw += __shfl_xor(aw, 16, 64); aw += __shfl_xor(aw, 32, 64);
    if (es == 0) {
      ushort4 o;
      o.x = (unsigned short)f2bf(ax * dn); o.y = (unsigned short)f2bf(ay * dn);
      o.z = (unsigned short)f2bf(az * dn); o.w = (unsigned short)f2bf(aw * dn);
      *(ushort4*)&X[wid][nd][fq * 4] = o;
    }
  }
  __syncthreads();

  // ---- phase B: [16 nodes] @ W via 8 MFMAs; epilogue optionally pre-scales for next layer ----
  const int g = es, r16 = fq;
  float bcol[4];
  #pragma unroll
  for (int c = 0; c < 4; ++c) bcol[c] = bias[c * 16 + r16];
  const bf16x8* wb = (const bf16x8*)Wl;
  f32x4 acc[4];
  #pragma unroll
  for (int c = 0; c < 4; ++c) acc[c] = (f32x4){bcol[c], bcol[c], bcol[c], bcol[c]};
  #pragma unroll
  for (int kk = 0; kk < 2; ++kk) {
    bf16x8 a = *(const bf16x8*)&X[wid][r16][kk * 32 + 8 * g];
    #pragma unroll
    for (int c = 0; c < 4; ++c)
      acc[c] = __builtin_amdgcn_mfma_f32_16x16x32_bf16(a, wb[(kk * 4 + c) * 64 + lane], acc[c], 0, 0, 0);
  }
  #pragma unroll
  for (int rr = 0; rr < 4; ++rr) {
    int orow = base + g * 4 + rr;
    if (orow < n) {
      float so = SCALE_OUT ? rsqrtf((float)(deg[orow] + 1u)) : 1.f;
      unsigned short* cp = h_out + (size_t)orow * 64 + r16;
      cp[0]  = (unsigned short)f2bf(fmaxf(acc[0][rr], 0.f) * so);
      cp[16] = (unsigned short)f2bf(fmaxf(acc[1][rr], 0.f) * so);
      cp[32] = (unsigned short)f2bf(fmaxf(acc[2][rr], 0.f) * so);
      cp[48] = (unsigned short)f2bf(fmaxf(acc[3][rr], 0.f) * so);
    }
  }
}

// ---------------- edge MLP: swapped-operand MFMA, zero LDS, weights in registers ----------------
// NOTE: __launch_bounds__(256) only — R10: a min-waves arg crushes VGPR and
// evicts the 24 register-resident weight frags (FETCH 208MB->1.25GB, 4x slower).
__global__ __launch_bounds__(256) void edge_mlp_mfma_k(
    const unsigned short* __restrict__ hb, const float* __restrict__ ea,
    const int* __restrict__ src, const int* __restrict__ dst,
    const short* __restrict__ W1p, const short* __restrict__ W2p,
    const float* __restrict__ bm1, const float* __restrict__ bm2,
    const float* __restrict__ Wm3, const float* __restrict__ bm3,
    float* __restrict__ out, int E, int ntiles)
{
  const int tid  = threadIdx.x;
  const int lane = tid & 63;
  const int wid  = tid >> 6;
  const int g    = lane >> 4;
  const int r16  = lane & 15;

  bf16x8 w1f[20];
  #pragma unroll
  for (int t = 0; t < 20; ++t) w1f[t] = ((const bf16x8*)W1p)[t * 64 + lane];
  bf16x8 w2f[4];
  #pragma unroll
  for (int t = 0; t < 4; ++t) w2f[t] = ((const bf16x8*)W2p)[t * 64 + lane];

  f32x4 b1v[4];
  #pragma unroll
  for (int c = 0; c < 4; ++c) {
    float4 v = *(const float4*)(bm1 + 32 * (c >> 1) + 8 * g + 4 * (c & 1));
    b1v[c] = (f32x4){v.x, v.y, v.z, v.w};
  }
  f32x4 b2v[2];
  #pragma unroll
  for (int c = 0; c < 2; ++c) {
    float4 v = *(const float4*)(bm2 + c * 16 + 4 * g);
    b2v[c] = (f32x4){v.x, v.y, v.z, v.w};
  }
  float4 w3a[2], w3b[2];
  #pragma unroll
  for (int c = 0; c < 2; ++c) {
    w3a[c] = *(const float4*)(Wm3 + (c * 16 + 4 * g) * 2);
    w3b[c] = *(const float4*)(Wm3 + (c * 16 + 4 * g) * 2 + 4);
  }
  const float b30 = bm3[0], b31 = bm3[1];

  const int ngroups = (ntiles + 3) >> 2;
  if (blockIdx.x >= ngroups) return;

  int mye1, sl1, dl1;
  bf16x8 c_a0, c_a1, c_a2, c_a3;
  float4 c_e0, c_e1;
  {
    int e = (blockIdx.x * 4 + wid) * 16 + r16;
    int mye = (e < E) ? e : (E - 1);
    int sl = src[mye], dl = dst[mye];
    const bf16x8* hs = (const bf16x8*)(hb + (size_t)sl * 64);
    c_a0 = hs[g]; c_a1 = hs[4 + g];
    const bf16x8* hd = (const bf16x8*)(hb + (size_t)dl * 64);
    c_a2 = hd[g]; c_a3 = hd[4 + g];
    if (g < 2) {
      const float4* ep = (const float4*)(ea + (size_t)mye * 16 + 8 * g);
      c_e0 = ep[0]; c_e1 = ep[1];
    }
    int grp1 = blockIdx.x + gridDim.x;
    if (grp1 > ngroups - 1) grp1 = ngroups - 1;
    int e1 = (grp1 * 4 + wid) * 16 + r16;
    mye1 = (e1 < E) ? e1 : (E - 1);
    sl1 = src[mye1]; dl1 = dst[mye1];
  }

  for (int grp = blockIdx.x; grp < ngroups; grp += gridDim.x) {
    const int e0 = (grp * 4 + wid) * 16;

    bf16x8 n_a0, n_a1, n_a2, n_a3;
    float4 n_e0, n_e1;
    {
      const bf16x8* hs = (const bf16x8*)(hb + (size_t)sl1 * 64);
      n_a0 = hs[g]; n_a1 = hs[4 + g];
      const bf16x8* hd = (const bf16x8*)(hb + (size_t)dl1 * 64);
      n_a2 = hd[g]; n_a3 = hd[4 + g];
      if (g < 2) {
        const float4* ep = (const float4*)(ea + (size_t)mye1 * 16 + 8 * g);
        n_e0 = ep[0]; n_e1 = ep[1];
      }
    }
    int mye2, sl2, dl2;
    {
      int grp2 = grp + 2 * gridDim.x;
      if (grp2 > ngroups - 1) grp2 = ngroups - 1;
      int e2 = (grp2 * 4 + wid) * 16 + r16;
      mye2 = (e2 < E) ? e2 : (E - 1);
      sl2 = src[mye2]; dl2 = dst[mye2];
    }

    bf16x8 a4;
    if (g < 2) {
      u32x4 w;
      w[0] = cvtpk(c_e0.x, c_e0.y); w[1] = cvtpk(c_e0.z, c_e0.w);
      w[2] = cvtpk(c_e1.x, c_e1.y); w[3] = cvtpk(c_e1.z, c_e1.w);
      a4 = u2b(w);
    } else {
      a4 = (bf16x8){0, 0, 0, 0, 0, 0, 0, 0};
    }

    f32x4 acc[4];
    #pragma unroll
    for (int c = 0; c < 4; ++c) acc[c] = b1v[c];
    #pragma unroll
    for (int c = 0; c < 4; ++c) {
      acc[c] = __builtin_amdgcn_mfma_f32_16x16x32_bf16(w1f[0 * 4 + c], c_a0, acc[c], 0, 0, 0);
      acc[c] = __builtin_amdgcn_mfma_f32_16x16x32_bf16(w1f[1 * 4 + c], c_a1, acc[c], 0, 0, 0);
      acc[c] = __builtin_amdgcn_mfma_f32_16x16x32_bf16(w1f[2 * 4 + c], c_a2, acc[c], 0, 0, 0);
      acc[c] = __builtin_amdgcn_mfma_f32_16x16x32_bf16(w1f[3 * 4 + c], c_a3, acc[c], 0, 0, 0);
      acc[c] = __builtin_amdgcn_mfma_f32_16x16x32_bf16(w1f[4 * 4 + c], a4,   acc[c], 0, 0, 0);
    }

    u32x4 x0w, x1w;
    x0w[0] = cvtpk(fmaxf(acc[0][0], 0.f), fmaxf(acc[0][1], 0.f));
    x0w[1] = cvtpk(fmaxf(acc[0][2], 0.f), fmaxf(acc[0][3], 0.f));
    x0w[2] = cvtpk(fmaxf(acc[1][0], 0.f), fmaxf(acc[1][1], 0.f));
    x0w[3] = cvtpk(fmaxf(acc[1][2], 0.f), fmaxf(acc[1][3], 0.f));
    x1w[0] = cvtpk(fmaxf(acc[2][0], 0.f), fmaxf(acc[2][1], 0.f));
    x1w[1] = cvtpk(fmaxf(acc[2][2], 0.f), fmaxf(acc[2][3], 0.f));
    x1w[2] = cvtpk(fmaxf(acc[3][0], 0.f), fmaxf(acc[3][1], 0.f));
    x1w[3] = cvtpk(fmaxf(acc[3][2], 0.f), fmaxf(acc[3][3], 0.f));
    bf16x8 xa0 = u2b(x0w), xa1 = u2b(x1w);

    f32x4 acc2[2];
    #pragma unroll
    for (int c = 0; c < 2; ++c) acc2[c] = b2v[c];
    #pragma unroll
    for (int c = 0; c < 2; ++c) {
      acc2[c] = __builtin_amdgcn_mfma_f32_16x16x32_bf16(w2f[0 * 2 + c], xa0, acc2[c], 0, 0, 0);
      acc2[c] = __builtin_amdgcn_mfma_f32_16x16x32_bf16(w2f[1 * 2 + c], xa1, acc2[c], 0, 0, 0);
    }

    float p0 = 0.f, p1 = 0.f;
    #pragma unroll
    for (int c = 0; c < 2; ++c) {
      float v0 = fmaxf(acc2[c][0], 0.f);
      float v1 = fmaxf(acc2[c][1], 0.f);
      float v2 = fmaxf(acc2[c][2], 0.f);
      float v3 = fmaxf(acc2[c][3], 0.f);
      p0 = fmaf(v0, w3a[c].x, p0); p1 = fmaf(v0, w3a[c].y, p1);
      p0 = fmaf(v1, w3a[c].z, p0); p1 = fmaf(v1, w3a[c].w, p1);
      p0 = fmaf(v2, w3b[c].x, p0); p1 = fmaf(v2, w3b[c].y, p1);
      p0 = fmaf(v3, w3b[c].z, p0); p1 = fmaf(v3, w3b[c].w, p1);
    }
    p0 += __shfl_xor(p0, 16, 64); p0 += __shfl_xor(p0, 32, 64);
    p1 += __shfl_xor(p1, 16, 64); p1 += __shfl_xor(p1, 32, 64);
    if (g == 0) {
      int e = e0 + r16;
      if (e < E) {
        float2 o; o.x = p0 + b30; o.y = p1 + b31;
        *(float2*)(out + (size_t)e * 2) = o;
      }
    }

    c_a0 = n_a0; c_a1 = n_a1; c_a2 = n_a2; c_a3 = n_a3;
    c_e0 = n_e0; c_e1 = n_e1;
    mye1 = mye2; sl1 = sl2; dl1 = dl2;
  }
}

// ---------------- launch ----------------
extern "C" void kernel_launch(void* const* d_in, const int* in_sizes, int n_in,
                              void* d_out, int out_size, void* d_ws, size_t ws_size,
                              hipStream_t stream) {
  const float* x   = (const float*)d_in[0];
  const int*   ei  = (const int*)d_in[1];
  const float* ea  = (const float*)d_in[2];
  const float* W1  = (const float*)d_in[3];
  const float* b1  = (const float*)d_in[4];
  const float* W2  = (const float*)d_in[5];
  const float* b2  = (const float*)d_in[6];
  const float* W3  = (const float*)d_in[7];
  const float* b3  = (const float*)d_in[8];
  const float* Wm1 = (const float*)d_in[9];
  const float* bm1 = (const float*)d_in[10];
  const float* Wm2 = (const float*)d_in[11];
  const float* bm2 = (const float*)d_in[12];
  const float* Wm3 = (const float*)d_in[13];
  const float* bm3 = (const float*)d_in[14];

  const int N  = in_sizes[0] / 128;
  const int E  = in_sizes[1] / 2;
  const int* srcp = ei;
  const int* dstp = ei + E;

  float* ws = (float*)d_ws;
  size_t off = 0;
  unsigned* cursor  = (unsigned*)(ws + off);  off += (size_t)N;
  int*      csr_pad = (int*)(ws + off);       off += (size_t)N * 64;
  unsigned short* lin = (unsigned short*)(ws + off); off += (size_t)N * 32;
  unsigned short* hA  = (unsigned short*)(ws + off); off += (size_t)N * 32;
  unsigned short* hB  = (unsigned short*)(ws + off); off += (size_t)N * 32;
  short* We1p = (short*)(ws + off); off += 5120;
  short* We2p = (short*)(ws + off); off += 1024;

  const int gNode = (N + 63) / 64;
  const int gAgg  = (N + 3) / 4;
  const int ntiles = (E + 15) / 16;

  (void)hipMemsetAsync(cursor, 0, (size_t)N * 4, stream);

  fill_pad_k<<<2048, 256, 0, stream>>>(srcp, dstp, cursor, csr_pad, E, N);
  pack_edge_k<<<40, 256, 0, stream>>>(Wm1, Wm2, We1p, We2p);

  // layer 1: GEMM (inline W1 pack, fused fp32->bf16) then aggregate (pre-scaled out)
  node_mfma_k<<<gNode, 256, 0, stream>>>(x, W1, lin, N);
  agg_csr_k<<<gAgg, 256, 0, stream>>>(lin, cursor, csr_pad, b1, hA, N);
  // layers 2,3: fused agg+GEMM; pure-add inner loop (dinv folded)
  agg_gemm_k<1><<<gNode, 256, 0, stream>>>(hA, cursor, csr_pad, W2, b2, hB, N);
  agg_gemm_k<0><<<gNode, 256, 0, stream>>>(hB, cursor, csr_pad, W3, b3, hA, N);

  // edge classifier
  edge_mlp_mfma_k<<<2048, 256, 0, stream>>>(hA, ea, srcp, dstp, We1p, We2p,
      bm1, bm2, Wm3, bm3, (float*)d_out, E, ntiles);
}